// Round 3
// baseline (303.072 us; speedup 1.0000x reference)
//
#include <hip/hip_runtime.h>

typedef __attribute__((ext_vector_type(8))) short short8;
typedef __attribute__((ext_vector_type(4))) float f32x4;
typedef __attribute__((ext_vector_type(4))) unsigned short u16x4;

#define NN 2048
#define BNTOT 16384
#define KG2 448
#define NK1 15
#define NG1 8
#define NF1 64

static __device__ __forceinline__ unsigned short f2bf(float v) {
    union { float f; unsigned int u; } a; a.f = v;
    unsigned int u = a.u;
    u += 0x7fffu + ((u >> 16) & 1u);   // round-to-nearest-even
    return (unsigned short)(u >> 16);
}
static __device__ __forceinline__ float bf2f(unsigned short s) {
    union { float f; unsigned int u; } a; a.u = ((unsigned int)s) << 16;
    return a.f;
}
static __device__ __forceinline__ float sigmoidf_(float v) {
    return 1.f / (1.f + __expf(-v));
}

// ---------------------------------------------------------------------------
// prep: x, w2 fp32 -> bf16; zero the fused-final accumulator
// ---------------------------------------------------------------------------
__global__ __launch_bounds__(256) void prep_k(const float* __restrict__ x,
                                              const float* __restrict__ w2,
                                              unsigned short* __restrict__ xbf,
                                              unsigned short* __restrict__ w2bf,
                                              float* __restrict__ oacc) {
    const long total = 131072L + 917504L + 32768L;
    for (long i = (long)blockIdx.x * 256 + threadIdx.x; i < total;
         i += (long)gridDim.x * 256) {
        if (i < 131072L) xbf[i] = f2bf(x[i]);
        else if (i < 131072L + 917504L) w2bf[i - 131072L] = f2bf(w2[i - 131072L]);
        else oacc[i - 131072L - 917504L] = 0.f;
    }
}

// ---------------------------------------------------------------------------
// transpose+convert: St[e][n][k] = bf16(S[e][k][n]) for e in {0,1}
// ---------------------------------------------------------------------------
__global__ __launch_bounds__(256) void transpose_k(const float* __restrict__ S,
                                                   unsigned short* __restrict__ St) {
    __shared__ float t[32][33];
    const int e  = blockIdx.z;
    const int n0 = blockIdx.x * 32, k0 = blockIdx.y * 32;
    const int tx = threadIdx.x & 31, ty = threadIdx.x >> 5;
    const float* src = S + (long)e * NN * NN;
    unsigned short* dst = St + (long)e * NN * NN;
#pragma unroll
    for (int i = 0; i < 4; ++i)
        t[ty + i * 8][tx] = src[(long)(k0 + ty + i * 8) * NN + n0 + tx];
    __syncthreads();
#pragma unroll
    for (int i = 0; i < 4; ++i)
        dst[(long)(n0 + ty + i * 8) * NN + k0 + tx] = f2bf(t[tx][ty + i * 8]);
}

// ---------------------------------------------------------------------------
// GEMM, double-buffered 2-phase: C[M,N] = A[M,K](bf16 rm) @ Bt[N,K](bf16 rm)^T
// Both operands via global_load_lds (linear tiles); raw barriers + counted
// vmcnt so next-tile loads stay in flight across the barrier (T3/T4 minimum).
// EPI 0: bf16 store [row][2048] at z*o_bstride
// EPI 1: z2t bf16 [b*2048+n][448] scatter (+ optional chain bf16 rm)
// EPI 2: fused final: sigmoid(v+bias) -> dot with wlin -> atomicAdd oacc
// ---------------------------------------------------------------------------
template <int BM, int BN, int EPI>
__global__ __launch_bounds__(256) void gemm_k(
    const unsigned short* __restrict__ A, int lda, long a_bstride, int a_shr,
    const unsigned short* __restrict__ Bt, int ldb, long b_bstride,
    int K, void* __restrict__ outp, long o_bstride, int kbase,
    unsigned short* __restrict__ chain, const float* __restrict__ bias,
    const float* __restrict__ wlin) {
    constexpr int WM = BM / 2, WN = BN / 2;
    constexpr int MI = WM / 16, NI = WN / 16;
    constexpr int ACH = BM / 64, BCH = BN / 64;
    constexpr int LPT = ACH + BCH;  // loads in flight per thread per tile
    __shared__ __attribute__((aligned(16))) unsigned short Alds[2][BM * 32];
    __shared__ __attribute__((aligned(16))) unsigned short Blds[2][BN * 32];

    const int tid  = threadIdx.x;
    const int lane = tid & 63;
    const int wv   = tid >> 6;
    const int q    = lane >> 4;
    const int r    = lane & 15;
    const int wm   = (wv >> 1) * WM;
    const int wn   = (wv & 1) * WN;

    const int n0 = blockIdx.x * BN;
    const int m0 = blockIdx.y * BM;
    const int z  = blockIdx.z;

    const unsigned short* Ap = A + (long)(z >> a_shr) * a_bstride + (long)m0 * lda;
    const unsigned short* Bp = Bt + (long)(z & 1) * b_bstride + (long)n0 * ldb;

    f32x4 acc[MI][NI];
#pragma unroll
    for (int i = 0; i < MI; ++i)
#pragma unroll
        for (int j = 0; j < NI; ++j) acc[i][j] = (f32x4){0.f, 0.f, 0.f, 0.f};

    auto stage = [&](int k0, int buf) {
#pragma unroll
        for (int c = 0; c < ACH; ++c) {
            const int row = (tid >> 2) + c * 64;
            const unsigned short* gp = Ap + (long)row * lda + k0 + (tid & 3) * 8;
            char* lb = (char*)(&Alds[buf][0]) + c * 4096 + wv * 1024;
            __builtin_amdgcn_global_load_lds(
                (const __attribute__((address_space(1))) void*)gp,
                (__attribute__((address_space(3))) void*)lb, 16, 0, 0);
        }
#pragma unroll
        for (int c = 0; c < BCH; ++c) {
            const int row = (tid >> 2) + c * 64;
            const unsigned short* gp = Bp + (long)row * ldb + k0 + (tid & 3) * 8;
            char* lb = (char*)(&Blds[buf][0]) + c * 4096 + wv * 1024;
            __builtin_amdgcn_global_load_lds(
                (const __attribute__((address_space(1))) void*)gp,
                (__attribute__((address_space(3))) void*)lb, 16, 0, 0);
        }
    };

    auto compute = [&](int buf) {
        short8 af[MI], bfv[NI];
#pragma unroll
        for (int i = 0; i < MI; ++i)
            af[i] = *(const short8*)&Alds[buf][(wm + i * 16 + r) * 32 + q * 8];
#pragma unroll
        for (int j = 0; j < NI; ++j)
            bfv[j] = *(const short8*)&Blds[buf][(wn + j * 16 + r) * 32 + q * 8];
#pragma unroll
        for (int i = 0; i < MI; ++i)
#pragma unroll
            for (int j = 0; j < NI; ++j)
                acc[i][j] = __builtin_amdgcn_mfma_f32_16x16x32_bf16(
                    af[i], bfv[j], acc[i][j], 0, 0, 0);
    };

    const int NT = K >> 5;
    stage(0, 0);
    for (int t = 0; t + 1 < NT; ++t) {
        stage((t + 1) * 32, (t + 1) & 1);
        asm volatile("s_waitcnt vmcnt(%0)" ::"n"(LPT) : "memory");
        __builtin_amdgcn_s_barrier();
        compute(t & 1);
        __builtin_amdgcn_s_barrier();
    }
    asm volatile("s_waitcnt vmcnt(0)" ::: "memory");
    __builtin_amdgcn_s_barrier();
    compute((NT - 1) & 1);

    // C/D layout: col = lane&15 (=r), row = q*4 + e  (m89-verified)
    if constexpr (EPI == 2) {
        float wl0[NI], wl1[NI];
#pragma unroll
        for (int j = 0; j < NI; ++j) {
            const int nn = (n0 + wn + j * 16 + r) & (NN - 1);
            wl0[j] = wlin[nn];
            wl1[j] = wlin[NN + nn];
        }
        const int bb = (n0 + wn) >> 11;
        float* oa = (float*)outp + (long)bb * 4096;
#pragma unroll
        for (int i = 0; i < MI; ++i) {
#pragma unroll
            for (int e = 0; e < 4; ++e) {
                const int row = m0 + wm + i * 16 + q * 4 + e;
                const float bs = bias[row];
                float p0 = 0.f, p1 = 0.f;
#pragma unroll
                for (int j = 0; j < NI; ++j) {
                    const float s = sigmoidf_(acc[i][j][e] + bs);
                    p0 += s * wl0[j];
                    p1 += s * wl1[j];
                }
#pragma unroll
                for (int mk = 1; mk < 16; mk <<= 1) {
                    p0 += __shfl_xor(p0, mk);
                    p1 += __shfl_xor(p1, mk);
                }
                if (r == 0) {
                    atomicAdd(&oa[row * 2 + 0], p0);
                    atomicAdd(&oa[row * 2 + 1], p1);
                }
            }
        }
    } else {
#pragma unroll
        for (int i = 0; i < MI; ++i) {
#pragma unroll
            for (int j = 0; j < NI; ++j) {
                const int row0 = m0 + wm + i * 16 + q * 4;
                const int col  = n0 + wn + j * 16 + r;
                if constexpr (EPI == 0) {
                    unsigned short* o = (unsigned short*)outp + (long)z * o_bstride;
#pragma unroll
                    for (int e = 0; e < 4; ++e)
                        o[(long)(row0 + e) * NN + col] = f2bf(acc[i][j][e]);
                } else {
                    const int bb = row0 >> 6, gg = row0 & 63;  // rows = b*64+g
                    u16x4 pk;
                    pk[0] = f2bf(acc[i][j][0]); pk[1] = f2bf(acc[i][j][1]);
                    pk[2] = f2bf(acc[i][j][2]); pk[3] = f2bf(acc[i][j][3]);
                    *(u16x4*)&((unsigned short*)outp)[
                        ((long)(bb * NN + col)) * KG2 + (kbase + z) * 64 + gg] = pk;
                    if (chain) {
#pragma unroll
                        for (int e = 0; e < 4; ++e)
                            chain[(long)z * o_bstride + (long)(row0 + e) * NN + col] =
                                f2bf(acc[i][j][e]);
                    }
                }
            }
        }
    }
}

// ---------------------------------------------------------------------------
// combine1: h[b,f,n] = sigmoid(sum_k sum_g z1[b,k,g,n]*w1[f,k,g] + b1[f])
// writes A2 (bf16 rm [b*64+f][n]) and z2t k=0 slice [b*2048+n][448]
// ---------------------------------------------------------------------------
__global__ __launch_bounds__(256) void combine1_k(const float* __restrict__ x,
                                                  const unsigned short* __restrict__ xSbf,
                                                  const float* __restrict__ w1,
                                                  const float* __restrict__ b1,
                                                  unsigned short* __restrict__ A2,
                                                  unsigned short* __restrict__ z2t) {
    __shared__ float w1s[NF1 * NK1 * NG1];
    const int tid = threadIdx.x;
    for (int i = tid; i < NF1 * NK1 * NG1; i += 256) w1s[i] = w1[i];
    __syncthreads();

    const int b  = blockIdx.y;
    const int n  = blockIdx.x * 128 + (tid & 127);
    const int fh = tid >> 7;

    float accv[32];
#pragma unroll
    for (int f = 0; f < 32; ++f) accv[f] = 0.f;

    for (int k = 0; k < NK1; ++k) {
        float vv[NG1];
#pragma unroll
        for (int g = 0; g < NG1; ++g) {
            if (k == 0) vv[g] = x[(long)(b * 8 + g) * NN + n];
            else vv[g] = bf2f(xSbf[(long)(k - 1) * (64 * 2048) +
                                   (long)(b * 8 + g) * NN + n]);
        }
#pragma unroll
        for (int f = 0; f < 32; ++f) {
            const float* wp = &w1s[((fh * 32 + f) * NK1 + k) * NG1];
            float s = 0.f;
#pragma unroll
            for (int g = 0; g < NG1; ++g) s += vv[g] * wp[g];
            accv[f] += s;
        }
    }
    unsigned short hb[32];
#pragma unroll
    for (int f = 0; f < 32; ++f) {
        const int fg = fh * 32 + f;
        const float h = sigmoidf_(accv[f] + b1[fg]);
        hb[f] = f2bf(h);
        A2[(long)(b * 64 + fg) * NN + n] = hb[f];
    }
    const long zb = ((long)(b * NN + n)) * KG2 + fh * 32;
#pragma unroll
    for (int c = 0; c < 4; ++c) {
        short8 v;
#pragma unroll
        for (int jj = 0; jj < 8; ++jj) v[jj] = (short)hb[c * 8 + jj];
        *(short8*)&z2t[zb + c * 8] = v;
    }
}

// ---------------------------------------------------------------------------
// finish: y = |sigmoid(oacc + blin[o])|   (32768 elems, layout [b][f][o])
// ---------------------------------------------------------------------------
__global__ __launch_bounds__(256) void finish_k(const float* __restrict__ oacc,
                                                const float* __restrict__ blin,
                                                float* __restrict__ out) {
    const int i = blockIdx.x * 256 + threadIdx.x;
    if (i < 32768) out[i] = fabsf(sigmoidf_(oacc[i] + blin[i & 1]));
}

// ---------------------------------------------------------------------------
extern "C" void kernel_launch(void* const* d_in, const int* in_sizes, int n_in,
                              void* d_out, int out_size, void* d_ws, size_t ws_size,
                              hipStream_t stream) {
    const float* x      = (const float*)d_in[0];
    const float* terms1 = (const float*)d_in[1];  // slices 0,1 are S0,S1
    const float* w1     = (const float*)d_in[3];
    const float* b1     = (const float*)d_in[4];
    const float* w2     = (const float*)d_in[5];
    const float* b2     = (const float*)d_in[6];
    const float* wlin   = (const float*)d_in[7];
    const float* blin   = (const float*)d_in[8];
    float* out = (float*)d_out;

    char* ws = (char*)d_ws;
    unsigned short* xbf   = (unsigned short*)(ws + 0);          //   262144 B
    unsigned short* w2bf  = (unsigned short*)(ws + 262144);     //  1835008 B
    unsigned short* St    = (unsigned short*)(ws + 2097152);    // 16777216 B
    unsigned short* xSbf  = (unsigned short*)(ws + 18874368);   //  3670016 B
    unsigned short* A2    = (unsigned short*)(ws + 22544384);   //  2097152 B
    unsigned short* hS1bf = (unsigned short*)(ws + 24641536);   //  4194304 B
    unsigned short* z2t   = (unsigned short*)(ws + 28835840);   // 14680064 B
    float*          oacc  = (float*)(ws + 43515904);            //   131072 B

    const long SLICE = (long)NN * NN;
    const long XSL   = 64L * 2048;
    const long HSL   = 512L * 2048;

    // 1) fp32 -> bf16 (x, w2) + zero oacc; S0,S1 -> bf16 transposed [n][k]
    prep_k<<<1024, 256, 0, stream>>>(x, w2, xbf, w2bf, oacc);
    transpose_k<<<dim3(64, 64, 2), 256, 0, stream>>>(terms1, St);

    // 2) G1 chain: order 1, 2, 3  (M=64, N=2048, K=2048)
    gemm_k<64, 64, 0><<<dim3(32, 1, 2), 256, 0, stream>>>(
        xbf, NN, 0L, 30, St, NN, SLICE, NN, (void*)xSbf, XSL, 0, nullptr,
        nullptr, nullptr);
    gemm_k<64, 64, 0><<<dim3(32, 1, 4), 256, 0, stream>>>(
        xSbf, NN, XSL, 1, St, NN, SLICE, NN, (void*)(xSbf + 2 * XSL), XSL, 0,
        nullptr, nullptr, nullptr);
    gemm_k<64, 64, 0><<<dim3(32, 1, 8), 256, 0, stream>>>(
        xSbf + 2 * XSL, NN, XSL, 1, St, NN, SLICE, NN, (void*)(xSbf + 6 * XSL),
        XSL, 0, nullptr, nullptr, nullptr);

    // 3) layer-1 combine -> A2 (bf16 rm) + z2t k=0
    combine1_k<<<dim3(16, 8), 256, 0, stream>>>(x, xSbf, w1, b1, A2, z2t);

    // 4) G2 chain: hS1 = h@S (k=1..2 + chain), hS2 = hS1@S (k=3..6)
    gemm_k<64, 128, 1><<<dim3(16, 8, 2), 256, 0, stream>>>(
        A2, NN, 0L, 30, St, NN, SLICE, NN, (void*)z2t, HSL, 1, hS1bf,
        nullptr, nullptr);
    gemm_k<64, 128, 1><<<dim3(16, 8, 4), 256, 0, stream>>>(
        hS1bf, NN, HSL, 1, St, NN, SLICE, NN, (void*)z2t, 0L, 3, nullptr,
        nullptr, nullptr);

    // 5) G3 fused: oacc += wlin . sigmoid(w2 @ z2 + b2)   (M=2048,K=448,N=16384)
    gemm_k<128, 128, 2><<<dim3(128, 16, 1), 256, 0, stream>>>(
        w2bf, KG2, 0L, 30, z2t, KG2, 0L, KG2, (void*)oacc, 0L, 0, nullptr,
        b2, wlin);

    // 6) final sigmoid + abs
    finish_k<<<128, 256, 0, stream>>>(oacc, blin, out);
}

// Round 4
// 249.132 us; speedup vs baseline: 1.2165x; 1.2165x over previous
//
#include <hip/hip_runtime.h>

typedef __attribute__((ext_vector_type(8))) short short8;
typedef __attribute__((ext_vector_type(4))) float f32x4;
typedef __attribute__((ext_vector_type(4))) unsigned short u16x4;

#define NN 2048
#define BNTOT 16384
#define KG2 448
#define NK1 15
#define NG1 8
#define NF1 64

static __device__ __forceinline__ unsigned short f2bf(float v) {
    union { float f; unsigned int u; } a; a.f = v;
    unsigned int u = a.u;
    u += 0x7fffu + ((u >> 16) & 1u);   // round-to-nearest-even
    return (unsigned short)(u >> 16);
}
static __device__ __forceinline__ float bf2f(unsigned short s) {
    union { float f; unsigned int u; } a; a.u = ((unsigned int)s) << 16;
    return a.f;
}
static __device__ __forceinline__ float sigmoidf_(float v) {
    return 1.f / (1.f + __expf(-v));
}
template <int N> static __device__ __forceinline__ void waitvm() {
    asm volatile("s_waitcnt vmcnt(%0)" ::"n"(N) : "memory");
}

// ---------------------------------------------------------------------------
// prep+transpose merged: z<2 -> St[e][n][k]=bf16(S[e][k][n]); z==2 -> x,w2
// fp32->bf16 + zero oacc (grid-stride over 1081344 elems)
// ---------------------------------------------------------------------------
__global__ __launch_bounds__(256) void prep_k(const float* __restrict__ S,
                                              const float* __restrict__ x,
                                              const float* __restrict__ w2,
                                              unsigned short* __restrict__ St,
                                              unsigned short* __restrict__ xbf,
                                              unsigned short* __restrict__ w2bf,
                                              float* __restrict__ oacc) {
    if (blockIdx.z < 2) {
        __shared__ float t[32][33];
        const int e  = blockIdx.z;
        const int n0 = blockIdx.x * 32, k0 = blockIdx.y * 32;
        const int tx = threadIdx.x & 31, ty = threadIdx.x >> 5;
        const float* src = S + (long)e * NN * NN;
        unsigned short* dst = St + (long)e * NN * NN;
#pragma unroll
        for (int i = 0; i < 4; ++i)
            t[ty + i * 8][tx] = src[(long)(k0 + ty + i * 8) * NN + n0 + tx];
        __syncthreads();
#pragma unroll
        for (int i = 0; i < 4; ++i)
            dst[(long)(n0 + ty + i * 8) * NN + k0 + tx] = f2bf(t[tx][ty + i * 8]);
    } else {
        const long total = 131072L + 917504L + 32768L;
        const long nb = 64 * 64;
        for (long i = (long)(blockIdx.y * 64 + blockIdx.x) * 256 + threadIdx.x;
             i < total; i += nb * 256) {
            if (i < 131072L) xbf[i] = f2bf(x[i]);
            else if (i < 131072L + 917504L) w2bf[i - 131072L] = f2bf(w2[i - 131072L]);
            else oacc[i - 131072L - 917504L] = 0.f;
        }
    }
}

// ---------------------------------------------------------------------------
// GEMM: C[M,N] = A[M,K](bf16 rm) @ Bt[N,K](bf16 rm)^T, both via global_load_lds
// PIPE=1: classic m97 (__syncthreads, TLP-hidden) for big grids.
// PIPE=4: 3-tiles-ahead counted-vmcnt pipeline for latency-bound small grids.
// EPI 0: bf16 store [row][2048] at z*o_bstride
// EPI 1: z2t bf16 [b*2048+n][448] scatter (+ optional chain bf16 rm)
// EPI 2: fused final: sigmoid(v+bias) dot wlin -> LDS-reduce -> atomicAdd oacc
// ---------------------------------------------------------------------------
template <int BM, int BN, int EPI, int PIPE>
__global__ __launch_bounds__(256) void gemm_k(
    const unsigned short* __restrict__ A, int lda, long a_bstride, int a_shr,
    const unsigned short* __restrict__ Bt, int ldb, long b_bstride,
    int K, void* __restrict__ outp, long o_bstride, int kbase,
    unsigned short* __restrict__ chain, const float* __restrict__ bias,
    const float* __restrict__ wlin) {
    constexpr int WM = BM / 2, WN = BN / 2;
    constexpr int MI = WM / 16, NI = WN / 16;
    constexpr int ACH = BM / 64, BCH = BN / 64;
    constexpr int LPT = ACH + BCH;
    __shared__ __attribute__((aligned(16))) unsigned short Alds[PIPE][BM * 32];
    __shared__ __attribute__((aligned(16))) unsigned short Blds[PIPE][BN * 32];

    const int tid  = threadIdx.x;
    const int lane = tid & 63;
    const int wv   = tid >> 6;
    const int q    = lane >> 4;
    const int r    = lane & 15;
    const int wm   = (wv >> 1) * WM;
    const int wn   = (wv & 1) * WN;

    const int n0 = blockIdx.x * BN;
    const int m0 = blockIdx.y * BM;
    const int z  = blockIdx.z;

    const unsigned short* Ap = A + (long)(z >> a_shr) * a_bstride + (long)m0 * lda;
    const unsigned short* Bp = Bt + (long)(z & 1) * b_bstride + (long)n0 * ldb;

    f32x4 acc[MI][NI];
#pragma unroll
    for (int i = 0; i < MI; ++i)
#pragma unroll
        for (int j = 0; j < NI; ++j) acc[i][j] = (f32x4){0.f, 0.f, 0.f, 0.f};

    auto stage = [&](int k0, int buf) {
#pragma unroll
        for (int c = 0; c < ACH; ++c) {
            const int row = (tid >> 2) + c * 64;
            const unsigned short* gp = Ap + (long)row * lda + k0 + (tid & 3) * 8;
            char* lb = (char*)(&Alds[buf][0]) + c * 4096 + wv * 1024;
            __builtin_amdgcn_global_load_lds(
                (const __attribute__((address_space(1))) void*)gp,
                (__attribute__((address_space(3))) void*)lb, 16, 0, 0);
        }
#pragma unroll
        for (int c = 0; c < BCH; ++c) {
            const int row = (tid >> 2) + c * 64;
            const unsigned short* gp = Bp + (long)row * ldb + k0 + (tid & 3) * 8;
            char* lb = (char*)(&Blds[buf][0]) + c * 4096 + wv * 1024;
            __builtin_amdgcn_global_load_lds(
                (const __attribute__((address_space(1))) void*)gp,
                (__attribute__((address_space(3))) void*)lb, 16, 0, 0);
        }
    };

    auto compute = [&](int buf) {
        short8 af[MI], bfv[NI];
#pragma unroll
        for (int i = 0; i < MI; ++i)
            af[i] = *(const short8*)&Alds[buf][(wm + i * 16 + r) * 32 + q * 8];
#pragma unroll
        for (int j = 0; j < NI; ++j)
            bfv[j] = *(const short8*)&Blds[buf][(wn + j * 16 + r) * 32 + q * 8];
#pragma unroll
        for (int i = 0; i < MI; ++i)
#pragma unroll
            for (int j = 0; j < NI; ++j)
                acc[i][j] = __builtin_amdgcn_mfma_f32_16x16x32_bf16(
                    af[i], bfv[j], acc[i][j], 0, 0, 0);
    };

    const int NT = K >> 5;
    if constexpr (PIPE == 1) {
        for (int t = 0; t < NT; ++t) {
            stage(t * 32, 0);
            __syncthreads();           // compiler drains vmcnt(0) here (m97)
            compute(0);
            __syncthreads();
        }
    } else {
#pragma unroll
        for (int p = 0; p < PIPE - 1; ++p) stage(p * 32, p);
        int t = 0;
        for (; t < NT - (PIPE - 1); ++t) {
            stage((t + PIPE - 1) * 32, (t + PIPE - 1) & (PIPE - 1));
            waitvm<(PIPE - 1) * LPT>();
            __builtin_amdgcn_s_barrier();
            compute(t & (PIPE - 1));
            __builtin_amdgcn_s_barrier();
        }
#pragma unroll
        for (int u = PIPE - 2; u >= 0; --u, ++t) {
            if (u == 2) waitvm<2 * LPT>();
            else if (u == 1) waitvm<1 * LPT>();
            else waitvm<0>();
            __builtin_amdgcn_s_barrier();
            compute(t & (PIPE - 1));
            __builtin_amdgcn_s_barrier();
        }
    }

    // C/D layout: col = lane&15 (=r), row = q*4 + e  (m89-verified)
    if constexpr (EPI == 2) {
        __shared__ float ored[BM][2];
        for (int i = tid; i < BM; i += 256) { ored[i][0] = 0.f; ored[i][1] = 0.f; }
        __syncthreads();
        float wl0[NI], wl1[NI];
#pragma unroll
        for (int j = 0; j < NI; ++j) {
            const int nn = (n0 + wn + j * 16 + r) & (NN - 1);
            wl0[j] = wlin[nn];
            wl1[j] = wlin[NN + nn];
        }
#pragma unroll
        for (int i = 0; i < MI; ++i) {
#pragma unroll
            for (int e = 0; e < 4; ++e) {
                const int lrow = wm + i * 16 + q * 4 + e;
                const float bs = bias[m0 + lrow];
                float p0 = 0.f, p1 = 0.f;
#pragma unroll
                for (int j = 0; j < NI; ++j) {
                    const float s = sigmoidf_(acc[i][j][e] + bs);
                    p0 += s * wl0[j];
                    p1 += s * wl1[j];
                }
#pragma unroll
                for (int mk = 1; mk < 16; mk <<= 1) {
                    p0 += __shfl_xor(p0, mk);
                    p1 += __shfl_xor(p1, mk);
                }
                if (r == 0) {
                    atomicAdd(&ored[lrow][0], p0);
                    atomicAdd(&ored[lrow][1], p1);
                }
            }
        }
        __syncthreads();
        const int bb = n0 >> 11;
        float* oa = (float*)outp + (long)bb * 4096;
        for (int i = tid; i < BM; i += 256) {
            atomicAdd(&oa[(m0 + i) * 2 + 0], ored[i][0]);
            atomicAdd(&oa[(m0 + i) * 2 + 1], ored[i][1]);
        }
    } else {
#pragma unroll
        for (int i = 0; i < MI; ++i) {
#pragma unroll
            for (int j = 0; j < NI; ++j) {
                const int row0 = m0 + wm + i * 16 + q * 4;
                const int col  = n0 + wn + j * 16 + r;
                if constexpr (EPI == 0) {
                    unsigned short* o = (unsigned short*)outp + (long)z * o_bstride;
#pragma unroll
                    for (int e = 0; e < 4; ++e)
                        o[(long)(row0 + e) * NN + col] = f2bf(acc[i][j][e]);
                } else {
                    const int bb = row0 >> 6, gg = row0 & 63;  // rows = b*64+g
                    u16x4 pk;
                    pk[0] = f2bf(acc[i][j][0]); pk[1] = f2bf(acc[i][j][1]);
                    pk[2] = f2bf(acc[i][j][2]); pk[3] = f2bf(acc[i][j][3]);
                    *(u16x4*)&((unsigned short*)outp)[
                        ((long)(bb * NN + col)) * KG2 + (kbase + z) * 64 + gg] = pk;
                    if (chain) {
#pragma unroll
                        for (int e = 0; e < 4; ++e)
                            chain[(long)z * o_bstride + (long)(row0 + e) * NN + col] =
                                f2bf(acc[i][j][e]);
                    }
                }
            }
        }
    }
}

// ---------------------------------------------------------------------------
// combine1: h[b,f,n] = sigmoid(sum_k sum_g z1[b,k,g,n]*w1[f,k,g] + b1[f])
// writes A2 (bf16 rm [b*64+f][n]) and z2t k=0 slice [b*2048+n][448]
// ---------------------------------------------------------------------------
__global__ __launch_bounds__(256) void combine1_k(const float* __restrict__ x,
                                                  const unsigned short* __restrict__ xSbf,
                                                  const float* __restrict__ w1,
                                                  const float* __restrict__ b1,
                                                  unsigned short* __restrict__ A2,
                                                  unsigned short* __restrict__ z2t) {
    __shared__ float w1s[NF1 * NK1 * NG1];
    const int tid = threadIdx.x;
    for (int i = tid; i < NF1 * NK1 * NG1; i += 256) w1s[i] = w1[i];
    __syncthreads();

    const int b  = blockIdx.y;
    const int n  = blockIdx.x * 128 + (tid & 127);
    const int fh = tid >> 7;

    float accv[32];
#pragma unroll
    for (int f = 0; f < 32; ++f) accv[f] = 0.f;

    for (int k = 0; k < NK1; ++k) {
        float vv[NG1];
#pragma unroll
        for (int g = 0; g < NG1; ++g) {
            if (k == 0) vv[g] = x[(long)(b * 8 + g) * NN + n];
            else vv[g] = bf2f(xSbf[(long)(k - 1) * (64 * 2048) +
                                   (long)(b * 8 + g) * NN + n]);
        }
#pragma unroll
        for (int f = 0; f < 32; ++f) {
            const float* wp = &w1s[((fh * 32 + f) * NK1 + k) * NG1];
            float s = 0.f;
#pragma unroll
            for (int g = 0; g < NG1; ++g) s += vv[g] * wp[g];
            accv[f] += s;
        }
    }
    unsigned short hb[32];
#pragma unroll
    for (int f = 0; f < 32; ++f) {
        const int fg = fh * 32 + f;
        const float h = sigmoidf_(accv[f] + b1[fg]);
        hb[f] = f2bf(h);
        A2[(long)(b * 64 + fg) * NN + n] = hb[f];
    }
    const long zb = ((long)(b * NN + n)) * KG2 + fh * 32;
#pragma unroll
    for (int c = 0; c < 4; ++c) {
        short8 v;
#pragma unroll
        for (int jj = 0; jj < 8; ++jj) v[jj] = (short)hb[c * 8 + jj];
        *(short8*)&z2t[zb + c * 8] = v;
    }
}

// ---------------------------------------------------------------------------
// finish: y = |sigmoid(oacc + blin[o])|   (32768 elems, layout [b][f][o])
// ---------------------------------------------------------------------------
__global__ __launch_bounds__(256) void finish_k(const float* __restrict__ oacc,
                                                const float* __restrict__ blin,
                                                float* __restrict__ out) {
    const int i = blockIdx.x * 256 + threadIdx.x;
    if (i < 32768) out[i] = fabsf(sigmoidf_(oacc[i] + blin[i & 1]));
}

// ---------------------------------------------------------------------------
extern "C" void kernel_launch(void* const* d_in, const int* in_sizes, int n_in,
                              void* d_out, int out_size, void* d_ws, size_t ws_size,
                              hipStream_t stream) {
    const float* x      = (const float*)d_in[0];
    const float* terms1 = (const float*)d_in[1];  // slices 0,1 are S0,S1
    const float* w1     = (const float*)d_in[3];
    const float* b1     = (const float*)d_in[4];
    const float* w2     = (const float*)d_in[5];
    const float* b2     = (const float*)d_in[6];
    const float* wlin   = (const float*)d_in[7];
    const float* blin   = (const float*)d_in[8];
    float* out = (float*)d_out;

    char* ws = (char*)d_ws;
    unsigned short* xbf   = (unsigned short*)(ws + 0);          //   262144 B
    unsigned short* w2bf  = (unsigned short*)(ws + 262144);     //  1835008 B
    unsigned short* St    = (unsigned short*)(ws + 2097152);    // 16777216 B
    unsigned short* xSbf  = (unsigned short*)(ws + 18874368);   //  3670016 B
    unsigned short* A2    = (unsigned short*)(ws + 22544384);   //  2097152 B
    unsigned short* hS1bf = (unsigned short*)(ws + 24641536);   //  4194304 B
    unsigned short* z2t   = (unsigned short*)(ws + 28835840);   // 14680064 B
    float*          oacc  = (float*)(ws + 43515904);            //   131072 B

    const long SLICE = (long)NN * NN;
    const long XSL   = 64L * 2048;
    const long HSL   = 512L * 2048;

    // 1) merged prep: St transpose (z<2) + x/w2 cvt + oacc zero (z==2)
    prep_k<<<dim3(64, 64, 3), 256, 0, stream>>>(terms1, x, w2, St, xbf, w2bf, oacc);

    // 2) G1 chain (M=64, N=2048, K=2048), PIPE=4 deep prefetch
    gemm_k<64, 64, 0, 4><<<dim3(32, 1, 2), 256, 0, stream>>>(
        xbf, NN, 0L, 30, St, NN, SLICE, NN, (void*)xSbf, XSL, 0, nullptr,
        nullptr, nullptr);
    gemm_k<64, 64, 0, 4><<<dim3(32, 1, 4), 256, 0, stream>>>(
        xSbf, NN, XSL, 1, St, NN, SLICE, NN, (void*)(xSbf + 2 * XSL), XSL, 0,
        nullptr, nullptr, nullptr);
    gemm_k<64, 64, 0, 4><<<dim3(32, 1, 8), 256, 0, stream>>>(
        xSbf + 2 * XSL, NN, XSL, 1, St, NN, SLICE, NN, (void*)(xSbf + 6 * XSL),
        XSL, 0, nullptr, nullptr, nullptr);

    // 3) layer-1 combine -> A2 (bf16 rm) + z2t k=0
    combine1_k<<<dim3(16, 8), 256, 0, stream>>>(x, xSbf, w1, b1, A2, z2t);

    // 4) G2 chain, PIPE=4: hS1 = h@S (k=1..2 + chain), hS2 = hS1@S (k=3..6)
    gemm_k<64, 128, 1, 4><<<dim3(16, 8, 2), 256, 0, stream>>>(
        A2, NN, 0L, 30, St, NN, SLICE, NN, (void*)z2t, HSL, 1, hS1bf,
        nullptr, nullptr);
    gemm_k<64, 128, 1, 4><<<dim3(16, 8, 4), 256, 0, stream>>>(
        hS1bf, NN, HSL, 1, St, NN, SLICE, NN, (void*)z2t, 0L, 3, nullptr,
        nullptr, nullptr);

    // 5) G3 fused (PIPE=1 m97, TLP-hidden): oacc += wlin . sigmoid(w2@z2 + b2)
    gemm_k<128, 128, 2, 1><<<dim3(128, 16, 1), 256, 0, stream>>>(
        w2bf, KG2, 0L, 30, z2t, KG2, 0L, KG2, (void*)oacc, 0L, 0, nullptr,
        b2, wlin);

    // 6) final sigmoid + abs
    finish_k<<<128, 256, 0, stream>>>(oacc, blin, out);
}